// Round 13
// baseline (128.061 us; speedup 1.0000x reference)
//
#include <hip/hip_runtime.h>
#include <stdint.h>

#define NB 32
#define NA 48
#define HIN 64
#define EIN 32
#define HH 64
#define HG 16
#define NCELLS 5
#define GH 1024        // HG*HH
#define EROW 40        // shorts per staged E row (32 + 8 pad)
#define P6 6           // nodes per block (wave <-> node in GRU)
#define EMW 20         // words per lane-row in em_s (16 + 4 pad)

typedef __attribute__((ext_vector_type(8))) short short8;   // 8 x bf16
typedef __attribute__((ext_vector_type(4))) float float4v;  // 4 x f32

__device__ __forceinline__ unsigned short f2bf(float f) {
    union { float f; unsigned int u; } v; v.f = f;
    unsigned int u = v.u + 0x7FFF + ((v.u >> 16) & 1);      // RNE
    return (unsigned short)(u >> 16);
}
__device__ __forceinline__ float bf2f(unsigned short s) {
    union { unsigned int u; float f; } v; v.u = ((unsigned int)s) << 16;
    return v.f;
}

// Merged one-shot prep: W_e -> split-bf16 B-fragments; gate weights -> chunk-major float4.
__global__ __launch_bounds__(256) void prep(const float* __restrict__ W_e,
                                            const float* __restrict__ W_ih,
                                            const float* __restrict__ W_hh,
                                            unsigned short* __restrict__ hiB,
                                            unsigned short* __restrict__ loB,
                                            float4* __restrict__ gw4) {
    const int idx = blockIdx.x * 256 + threadIdx.x;
    if (idx < 32768) {
        const int ct = idx >> 9, l = (idx >> 3) & 63, jj = idx & 7;
        const int k = (l >> 4) * 8 + jj;
        const int c = ct * 16 + (l & 15);
        const float x = W_e[k * GH + c];
        const unsigned short hb = f2bf(x);
        hiB[idx] = hb;
        loB[idx] = f2bf(x - bf2f(hb));
    } else {
        const int o = idx - 32768;                 // 0..4095
        if (o < 20 * 192) {
            const int j = o / 192, c = o - j * 192;
            float4 v;
            if (j < 4)  v = *(const float4*)(W_ih + c * HG + 4 * j);
            else        v = *(const float4*)(W_hh + c * HH + 4 * (j - 4));
            gw4[o] = v;
        }
    }
}

// Edge phase for a GROUP OF 3 nodes (pg = 0 or 3), group-uniform tile count NT.
// Zero-padded rows contribute exactly max(be,0); subtract (16*NT - cnt)*max(be,0)
// once per column, AFTER the quad reduction.
template <int NT>
__device__ __forceinline__ void edge3(
    const unsigned short* __restrict__ hiB, const unsigned short* __restrict__ loB,
    const float* __restrict__ b_e,
    const unsigned short* EcolH, const unsigned short* EcolL,
    const int* cnt_s, float* em_s,
    int wave, int lane, int mrow, int quad, int pg)
{
    const float4v zero4 = {0.0f, 0.0f, 0.0f, 0.0f};
    short8 aH[3][NT ? NT : 1], aL[3][NT ? NT : 1];
    float finv[3];
    #pragma unroll
    for (int p = 0; p < 3; ++p) {
        finv[p] = (float)(16 * NT - cnt_s[pg + p]);
        #pragma unroll
        for (int rt = 0; rt < NT; ++rt) {
            const int off = ((pg + p) * NA + 16 * rt + mrow) * EROW + quad * 8;
            aH[p][rt] = *(const short8*)(EcolH + off);
            aL[p][rt] = *(const short8*)(EcolL + off);
        }
    }
    #pragma unroll 2
    for (int ct = wave; ct < 64; ct += P6) {
        const short8 bfH = *(const short8*)(hiB + (size_t)ct * 512 + lane * 8);
        const short8 bfL = *(const short8*)(loB + (size_t)ct * 512 + lane * 8);
        const float be = b_e[ct * 16 + mrow];
        const float bneg = fmaxf(be, 0.0f);
        const int ldst = (16 * (ct & 3) + (ct >> 2)) * EMW;
        #pragma unroll
        for (int p = 0; p < 3; ++p) {
            float ps = 0.0f;
            #pragma unroll
            for (int rt = 0; rt < NT; ++rt) {
                float4v d = __builtin_amdgcn_mfma_f32_16x16x32_bf16(aL[p][rt], bfH, zero4, 0, 0, 0);
                d = __builtin_amdgcn_mfma_f32_16x16x32_bf16(aH[p][rt], bfL, d, 0, 0, 0);
                d = __builtin_amdgcn_mfma_f32_16x16x32_bf16(aH[p][rt], bfH, d, 0, 0, 0);
                ps += fmaxf(d[0] + be, 0.0f);
                ps += fmaxf(d[1] + be, 0.0f);
                ps += fmaxf(d[2] + be, 0.0f);
                ps += fmaxf(d[3] + be, 0.0f);
            }
            ps += __shfl_xor(ps, 16);
            ps += __shfl_xor(ps, 32);
            ps = fmaf(finv[p], -bneg, ps);      // once per column (post-reduce)
            if (lane < 16)
                em_s[(pg + p) * 1280 + ldst + lane] = ps;
        }
    }
}

__device__ __forceinline__ int max3i(int a, int b, int c) {
    int m = a > b ? a : b; return m > c ? m : c;
}

// One block per 6 nodes; 384 threads (6 waves); grid 256 = 1 block/CU.
// __launch_bounds__(384, 1): LDS (138.5 KB) already caps at 1 block/CU = 1.5
// waves/EU, so a VGPR cap buys NOTHING. R11/R12's (384,2) made the allocator
// pin 128 VGPRs (occupancy step) and spill ~40 regs/thread once = the 15 MB
// WRITE_SIZE. Uncapping lets ~170 live values stay resident.
__global__ __launch_bounds__(384, 1) void fused_kernel(
    const float* __restrict__ A,  const float* __restrict__ h,
    const float* __restrict__ E,
    const float* __restrict__ W_h, const float* __restrict__ b_h,
    const float* __restrict__ b_e,
    const float* __restrict__ b_ih, const float* __restrict__ b_hh,
    const unsigned short* __restrict__ hiB, const unsigned short* __restrict__ loB,
    const float4* __restrict__ gw4,
    float* __restrict__ out)
{
    __shared__ float gw_sf[20 * 192 * 4];             // 61.4 KB gate weights (chunk-major)
    __shared__ unsigned short EcolH[P6 * NA * EROW];  // 23 KB
    __shared__ unsigned short EcolL[P6 * NA * EROW];  // 23 KB
    __shared__ float em_s[P6 * 1280];                 // 30.7 KB Esum in em-layout
    __shared__ float hcbuf[P6 * HH];
    __shared__ float Mbuf[P6 * HG];
    __shared__ int   ilist[P6 * NA];
    __shared__ int   cnt_s[P6];

    const int node0 = blockIdx.x * P6;
    const int b = node0 / NA, j0 = node0 - b * NA;
    const int tid = threadIdx.x, lane = tid & 63, wave = tid >> 6;
    const int mrow = lane & 15, quad = lane >> 4;

    // ---- stage gate weights -> LDS first (loads overlap ballot below) ----
    for (int idx = tid; idx < 20 * 192; idx += 384)
        *(float4*)(gw_sf + idx * 4) = gw4[idx];

    // ---- ballot: wave w builds node w's compacted active-row list ----
    {
        const float a = (lane < NA) ? A[((size_t)b * NA + lane) * NA + (j0 + wave)] : 0.0f;
        const unsigned long long m = __ballot(a != 0.0f);
        if (a != 0.0f) ilist[wave * NA + __popcll(m & ((1ull << lane) - 1ull))] = lane;
        if (lane == 0) cnt_s[wave] = (int)__popcll(m);
    }
    __syncthreads();

    // ---- stage compacted E rows -> split bf16 LDS; zero-pad rows >= cnt ----
    for (int idx = tid; idx < P6 * NA * 8; idx += 384) {
        const int p = idx / (NA * 8);
        const int rem = idx - p * (NA * 8);
        const int r = rem >> 3, q = rem & 7;
        uint2 hv2 = make_uint2(0u, 0u), lv2 = make_uint2(0u, 0u);
        if (r < cnt_s[p]) {
            const int i = ilist[p * NA + r];
            const float4 ev = *(const float4*)(E + ((size_t)(b * NA + i) * NA + (j0 + p)) * EIN + 4 * q);
            unsigned short h0 = f2bf(ev.x), h1 = f2bf(ev.y), h2 = f2bf(ev.z), h3 = f2bf(ev.w);
            unsigned short l0 = f2bf(ev.x - bf2f(h0)), l1 = f2bf(ev.y - bf2f(h1));
            unsigned short l2 = f2bf(ev.z - bf2f(h2)), l3 = f2bf(ev.w - bf2f(h3));
            hv2 = make_uint2((unsigned int)h0 | ((unsigned int)h1 << 16),
                             (unsigned int)h2 | ((unsigned int)h3 << 16));
            lv2 = make_uint2((unsigned int)l0 | ((unsigned int)l1 << 16),
                             (unsigned int)l2 | ((unsigned int)l3 << 16));
        }
        *(uint2*)(&EcolH[(p * NA + r) * EROW + 4 * q]) = hv2;
        *(uint2*)(&EcolL[(p * NA + r) * EROW + 4 * q]) = lv2;
    }
    __syncthreads();

    // ---- edge phase: two groups of 3 nodes ----
    const int ntg0 = max3i((cnt_s[0] + 15) >> 4, (cnt_s[1] + 15) >> 4, (cnt_s[2] + 15) >> 4);
    const int ntg1 = max3i((cnt_s[3] + 15) >> 4, (cnt_s[4] + 15) >> 4, (cnt_s[5] + 15) >> 4);
    if (ntg0 == 1)      edge3<1>(hiB, loB, b_e, EcolH, EcolL, cnt_s, em_s, wave, lane, mrow, quad, 0);
    else if (ntg0 == 2) edge3<2>(hiB, loB, b_e, EcolH, EcolL, cnt_s, em_s, wave, lane, mrow, quad, 0);
    else if (ntg0 == 3) edge3<3>(hiB, loB, b_e, EcolH, EcolL, cnt_s, em_s, wave, lane, mrow, quad, 0);
    else
        for (int idx = tid; idx < 3 * 1280; idx += 384) em_s[idx] = 0.0f;
    if (ntg1 == 1)      edge3<1>(hiB, loB, b_e, EcolH, EcolL, cnt_s, em_s, wave, lane, mrow, quad, 3);
    else if (ntg1 == 2) edge3<2>(hiB, loB, b_e, EcolH, EcolL, cnt_s, em_s, wave, lane, mrow, quad, 3);
    else if (ntg1 == 3) edge3<3>(hiB, loB, b_e, EcolH, EcolL, cnt_s, em_s, wave, lane, mrow, quad, 3);
    else
        for (int idx = tid; idx < 3 * 1280; idx += 384) em_s[3 * 1280 + idx] = 0.0f;

    // hv = relu(h @ W_h + b_h) * maskh  -> hc register (wave w owns node w)
    const int node = node0 + wave;
    float hc;
    {
        const float a = (lane < NA) ? A[(size_t)node * NA + lane] : 0.0f;
        const unsigned long long mrowm = __ballot(a != 0.0f);
        const float maskh = (mrowm != 0ull) ? 1.0f : 0.0f;
        const float hr = h[(size_t)node * HIN + lane];
        float acc = b_h[lane];
        #pragma unroll
        for (int k = 0; k < HIN; ++k)
            acc = fmaf(__shfl(hr, k), W_h[k * HH + lane], acc);
        hc = fmaxf(acc, 0.0f) * maskh;
    }
    __syncthreads();   // em_s fully written (edge is cross-wave) before GRU reads

    // ---- GRU: barrier-free, wave-private ----
    float4v em4[4];
    #pragma unroll
    for (int kk = 0; kk < 4; ++kk)
        em4[kk] = *(const float4v*)(em_s + wave * 1280 + lane * EMW + 4 * kk);
    const float bihr = b_ih[lane], bihz = b_ih[HH + lane], bihn = b_ih[2 * HH + lane];
    const float bhhr = b_hh[lane], bhhz = b_hh[HH + lane], bhhn = b_hh[2 * HH + lane];
    float* hcb = hcbuf + wave * HH;
    float* Mb  = Mbuf + wave * HG;
    const int q16 = quad * 16;

    #pragma unroll 1
    for (int it = 0; it < NCELLS; ++it) {
        hcb[lane] = hc;                                  // wave-local; waitcnt only
        float pp;
        {
            const float4v ha = *(const float4v*)(hcb + q16);
            const float4v hb = *(const float4v*)(hcb + q16 + 4);
            const float4v hcv = *(const float4v*)(hcb + q16 + 8);
            const float4v hd = *(const float4v*)(hcb + q16 + 12);
            pp = em4[0][0] * ha[0];
            pp = fmaf(em4[0][1], ha[1], pp); pp = fmaf(em4[0][2], ha[2], pp); pp = fmaf(em4[0][3], ha[3], pp);
            pp = fmaf(em4[1][0], hb[0], pp); pp = fmaf(em4[1][1], hb[1], pp);
            pp = fmaf(em4[1][2], hb[2], pp); pp = fmaf(em4[1][3], hb[3], pp);
            pp = fmaf(em4[2][0], hcv[0], pp); pp = fmaf(em4[2][1], hcv[1], pp);
            pp = fmaf(em4[2][2], hcv[2], pp); pp = fmaf(em4[2][3], hcv[3], pp);
            pp = fmaf(em4[3][0], hd[0], pp); pp = fmaf(em4[3][1], hd[1], pp);
            pp = fmaf(em4[3][2], hd[2], pp); pp = fmaf(em4[3][3], hd[3], pp);
        }
        pp += __shfl_xor(pp, 16);
        pp += __shfl_xor(pp, 32);                        // M[g] at every lane (g=lane&15)
        if (lane < 16) Mb[lane] = pp;
        float4v M4[4];
        #pragma unroll
        for (int kk = 0; kk < 4; ++kk) M4[kk] = *(const float4v*)(Mb + 4 * kk);

        float gir = bihr, giz = bihz, gin = bihn;
        #pragma unroll
        for (int j = 0; j < 4; ++j) {
            const float4v wr = *(const float4v*)(gw_sf + (j * 192 + lane) * 4);
            const float4v wz = *(const float4v*)(gw_sf + (j * 192 + 64 + lane) * 4);
            const float4v wn = *(const float4v*)(gw_sf + (j * 192 + 128 + lane) * 4);
            gir = fmaf(M4[j][0], wr[0], gir); gir = fmaf(M4[j][1], wr[1], gir);
            gir = fmaf(M4[j][2], wr[2], gir); gir = fmaf(M4[j][3], wr[3], gir);
            giz = fmaf(M4[j][0], wz[0], giz); giz = fmaf(M4[j][1], wz[1], giz);
            giz = fmaf(M4[j][2], wz[2], giz); giz = fmaf(M4[j][3], wz[3], giz);
            gin = fmaf(M4[j][0], wn[0], gin); gin = fmaf(M4[j][1], wn[1], gin);
            gin = fmaf(M4[j][2], wn[2], gin); gin = fmaf(M4[j][3], wn[3], gin);
        }
        float ghr = bhhr, ghz = bhhz, ghn = bhhn;
        #pragma unroll
        for (int j = 0; j < 16; ++j) {
            const float4v h4 = *(const float4v*)(hcb + 4 * j);       // broadcast
            const float4v wr = *(const float4v*)(gw_sf + ((j + 4) * 192 + lane) * 4);
            const float4v wz = *(const float4v*)(gw_sf + ((j + 4) * 192 + 64 + lane) * 4);
            const float4v wn = *(const float4v*)(gw_sf + ((j + 4) * 192 + 128 + lane) * 4);
            ghr = fmaf(h4[0], wr[0], ghr); ghr = fmaf(h4[1], wr[1], ghr);
            ghr = fmaf(h4[2], wr[2], ghr); ghr = fmaf(h4[3], wr[3], ghr);
            ghz = fmaf(h4[0], wz[0], ghz); ghz = fmaf(h4[1], wz[1], ghz);
            ghz = fmaf(h4[2], wz[2], ghz); ghz = fmaf(h4[3], wz[3], ghz);
            ghn = fmaf(h4[0], wn[0], ghn); ghn = fmaf(h4[1], wn[1], ghn);
            ghn = fmaf(h4[2], wn[2], ghn); ghn = fmaf(h4[3], wn[3], ghn);
        }
        const float r = 1.0f / (1.0f + __expf(-(gir + ghr)));
        const float z = 1.0f / (1.0f + __expf(-(giz + ghz)));
        const float nin = gin + r * ghn;
        const float n = 1.0f - 2.0f / (__expf(2.0f * nin) + 1.0f);   // tanh
        hc = (1.0f - z) * n + z * hc;
    }

    out[(size_t)node * HH + lane] = hc;
}

extern "C" void kernel_launch(void* const* d_in, const int* in_sizes, int n_in,
                              void* d_out, int out_size, void* d_ws, size_t ws_size,
                              hipStream_t stream) {
    const float* A    = (const float*)d_in[0];
    const float* h    = (const float*)d_in[1];
    const float* E    = (const float*)d_in[2];
    const float* W_h  = (const float*)d_in[3];
    const float* b_h  = (const float*)d_in[4];
    const float* W_e  = (const float*)d_in[5];
    const float* b_e  = (const float*)d_in[6];
    const float* W_ih = (const float*)d_in[7];
    const float* b_ih = (const float*)d_in[8];
    const float* W_hh = (const float*)d_in[9];
    const float* b_hh = (const float*)d_in[10];
    unsigned short* hiB = (unsigned short*)d_ws;            // 64 KB
    unsigned short* loB = hiB + 32768;                      // 64 KB
    float4* gw4 = (float4*)(loB + 32768);                   // 61.4 KB
    float* out = (float*)d_out;

    hipLaunchKernelGGL(prep, dim3(144), dim3(256), 0, stream,
                       W_e, W_ih, W_hh, hiB, loB, gw4);
    hipLaunchKernelGGL(fused_kernel, dim3(NB * NA / P6), dim3(384), 0, stream,
                       A, h, E, W_h, b_h, b_e, b_ih, b_hh, hiB, loB, gw4, out);
}

// Round 14
// 104.535 us; speedup vs baseline: 1.2250x; 1.2250x over previous
//
#include <hip/hip_runtime.h>
#include <stdint.h>

#define NB 32
#define NA 48
#define HIN 64
#define EIN 32
#define HH 64
#define HG 16
#define NCELLS 5
#define GH 1024        // HG*HH
#define EROW 40        // shorts per staged E row (32 + 8 pad; 80 B, 16B-aligned rows)
#define P3 3           // nodes per block
#define ESTR 1088      // Esum_s floats per node (16 rows x 68 padded)

typedef __attribute__((ext_vector_type(8))) short short8;   // 8 x bf16 (4 VGPRs)
typedef __attribute__((ext_vector_type(4))) float float4v;  // 4 x f32

__device__ __forceinline__ unsigned short f2bf(float f) {
    union { float f; unsigned int u; } v; v.f = f;
    unsigned int u = v.u + 0x7FFF + ((v.u >> 16) & 1);      // RNE
    return (unsigned short)(u >> 16);
}
__device__ __forceinline__ float bf2f(unsigned short s) {
    union { unsigned int u; float f; } v; v.u = ((unsigned int)s) << 16;
    return v.f;
}

// Merged one-shot prep: W_e -> split-bf16 MFMA B-fragments; gate weights ->
// chunk-major float4 (coalesced 16B/lane streams for the GRU gate loop).
__global__ __launch_bounds__(256) void prep(const float* __restrict__ W_e,
                                            const float* __restrict__ W_ih,
                                            const float* __restrict__ W_hh,
                                            unsigned short* __restrict__ hiB,
                                            unsigned short* __restrict__ loB,
                                            float4* __restrict__ gw4) {
    const int idx = blockIdx.x * 256 + threadIdx.x;
    if (idx < 32768) {
        const int ct = idx >> 9, l = (idx >> 3) & 63, jj = idx & 7;
        const int k = (l >> 4) * 8 + jj;
        const int c = ct * 16 + (l & 15);
        const float x = W_e[k * GH + c];
        const unsigned short hb = f2bf(x);
        hiB[idx] = hb;
        loB[idx] = f2bf(x - bf2f(hb));
    } else {
        const int o = idx - 32768;                 // 0..4095
        if (o < 20 * 192) {
            const int j = o / 192, c = o - j * 192;
            float4 v;
            if (j < 4)  v = *(const float4*)(W_ih + c * HG + 4 * j);
            else        v = *(const float4*)(W_hh + c * HH + 4 * (j - 4));
            gw4[o] = v;
        }
    }
}

// Edge phase for 3 nodes, specialized on block-uniform max tile count NTMAX.
// One bfrag load serves all 3 nodes (B traffic /3). Masks via LDS broadcast.
// All register arrays constant-indexed (R4 lesson: runtime-indexed register
// arrays spill to scratch).
template <int NTMAX>
__device__ __forceinline__ void edge_phase3(
    const unsigned short* __restrict__ hiB, const unsigned short* __restrict__ loB,
    const float* __restrict__ b_e,
    const unsigned short* EcolH, const unsigned short* EcolL,   // [3][48][EROW]
    const float* mask_s,                                        // [3][48]
    int wave, int lane, int mrow, int quad,
    float* Esum_s)                                              // [3][ESTR]
{
    const float4v zero4 = {0.0f, 0.0f, 0.0f, 0.0f};
    short8 aH[P3][NTMAX ? NTMAX : 1], aL[P3][NTMAX ? NTMAX : 1];
    #pragma unroll
    for (int p = 0; p < P3; ++p)
        #pragma unroll
        for (int rt = 0; rt < NTMAX; ++rt) {
            const int off = (p * 48 + 16 * rt + mrow) * EROW + quad * 8;
            aH[p][rt] = *(const short8*)(EcolH + off);
            aL[p][rt] = *(const short8*)(EcolL + off);
        }

    #pragma unroll 4
    for (int t = 0; t < 16; ++t) {
        const int ct = wave * 16 + t;
        const short8 bfH = *(const short8*)(hiB + (size_t)ct * 512 + lane * 8);
        const short8 bfL = *(const short8*)(loB + (size_t)ct * 512 + lane * 8);
        const float be = b_e[ct * 16 + mrow];   // L1-hot, 16-lane broadcast
        float psum[P3] = {0.0f, 0.0f, 0.0f};
        #pragma unroll
        for (int p = 0; p < P3; ++p) {
            #pragma unroll
            for (int rt = 0; rt < NTMAX; ++rt) {
                // split-bf16: A_lo*B_hi + A_hi*B_lo + A_hi*B_hi (fp32 acc)
                float4v d = __builtin_amdgcn_mfma_f32_16x16x32_bf16(aL[p][rt], bfH, zero4, 0, 0, 0);
                d = __builtin_amdgcn_mfma_f32_16x16x32_bf16(aH[p][rt], bfL, d, 0, 0, 0);
                d = __builtin_amdgcn_mfma_f32_16x16x32_bf16(aH[p][rt], bfH, d, 0, 0, 0);
                const float4v mk = *(const float4v*)(mask_s + p * 48 + rt * 16 + quad * 4);
                #pragma unroll
                for (int rg = 0; rg < 4; ++rg)
                    psum[p] = fmaf(fmaxf(d[rg] + be, 0.0f), mk[rg], psum[p]);
            }
        }
        #pragma unroll
        for (int p = 0; p < P3; ++p) {
            float ps = psum[p];
            ps += __shfl_xor(ps, 16);
            ps += __shfl_xor(ps, 32);
            if (lane < 16) {
                const int c = ct * 16 + lane;
                Esum_s[p * ESTR + (c >> 6) * 68 + (c & 63)] = ps;
            }
        }
    }
}

// One block per 3 nodes. Grid 512 = exactly 2 blocks/CU (balanced, one round).
// This is the session's best-measured configuration (R9: fused ~37 us, VGPR 52,
// no spill). P6/1-block-per-CU variants (R11-R13) all regressed to 53-55 us.
__global__ __launch_bounds__(256, 2) void fused_kernel(
    const float* __restrict__ A,  const float* __restrict__ h,
    const float* __restrict__ E,
    const float* __restrict__ W_h, const float* __restrict__ b_h,
    const float* __restrict__ b_e,
    const float* __restrict__ b_ih, const float* __restrict__ b_hh,
    const unsigned short* __restrict__ hiB, const unsigned short* __restrict__ loB,
    const float4* __restrict__ gw4,
    float* __restrict__ out)
{
    __shared__ unsigned short EcolH[P3 * NA * EROW];  // compacted E rows, bf16 hi
    __shared__ unsigned short EcolL[P3 * NA * EROW];  // bf16 lo (residual)
    __shared__ float Esum_s[P3 * ESTR];
    __shared__ float mask_s[P3 * 48];                 // [p][row] validity
    __shared__ int   ilist[P3 * NA];
    __shared__ int   cnt_s[P3];
    __shared__ float hc_s[P3 * HH];
    __shared__ float M_s[P3 * HG];
    __shared__ float gsum_s[P3 * 2 * HH];
    __shared__ float gin_s[P3 * HH], ghn_s[P3 * HH];

    const int node0 = blockIdx.x * P3;          // 3 nodes share batch b (48%3==0)
    const int b = node0 / NA, j0 = node0 - b * NA;
    const int tid = threadIdx.x, lane = tid & 63, wave = tid >> 6;
    const int mrow = lane & 15, quad = lane >> 4;

    // ---- ballot phase: waves 0..2 build compacted active-row lists ----
    if (wave < P3) {
        const float a = (lane < NA) ? A[((size_t)b * NA + lane) * NA + (j0 + wave)] : 0.0f;
        const unsigned long long m = __ballot(a != 0.0f);
        if (a != 0.0f) ilist[wave * NA + __popcll(m & ((1ull << lane) - 1ull))] = lane;
        if (lane == 0) cnt_s[wave] = (int)__popcll(m);
    }
    __syncthreads();

    // ---- stage compacted E rows -> split bf16 LDS; zero-pad rows >= cnt ----
    for (int idx = tid; idx < P3 * NA * 8; idx += 256) {
        const int p = idx / (NA * 8);
        const int rem = idx - p * (NA * 8);
        const int r = rem >> 3, q = rem & 7;
        uint2 hv2 = make_uint2(0u, 0u), lv2 = make_uint2(0u, 0u);
        if (r < cnt_s[p]) {
            const int i = ilist[p * NA + r];
            const float4 ev = *(const float4*)(E + ((size_t)(b * NA + i) * NA + (j0 + p)) * EIN + 4 * q);
            unsigned short h0 = f2bf(ev.x), h1 = f2bf(ev.y), h2 = f2bf(ev.z), h3 = f2bf(ev.w);
            unsigned short l0 = f2bf(ev.x - bf2f(h0)), l1 = f2bf(ev.y - bf2f(h1));
            unsigned short l2 = f2bf(ev.z - bf2f(h2)), l3 = f2bf(ev.w - bf2f(h3));
            hv2 = make_uint2((unsigned int)h0 | ((unsigned int)h1 << 16),
                             (unsigned int)h2 | ((unsigned int)h3 << 16));
            lv2 = make_uint2((unsigned int)l0 | ((unsigned int)l1 << 16),
                             (unsigned int)l2 | ((unsigned int)l3 << 16));
        }
        *(uint2*)(&EcolH[(p * NA + r) * EROW + 4 * q]) = hv2;
        *(uint2*)(&EcolL[(p * NA + r) * EROW + 4 * q]) = lv2;
    }
    // validity masks for the MFMA epilogue
    if (tid < P3 * 48) {
        const int p = tid / 48, rem = tid - p * 48;
        mask_s[tid] = (rem < cnt_s[p]) ? 1.0f : 0.0f;   // rem = rt*16+ri = global row
    }
    __syncthreads();

    const int nt0 = (cnt_s[0] + 15) >> 4, nt1 = (cnt_s[1] + 15) >> 4, nt2 = (cnt_s[2] + 15) >> 4;
    int ntmax = nt0 > nt1 ? nt0 : nt1; ntmax = ntmax > nt2 ? ntmax : nt2;   // block-uniform

    if (ntmax == 0)
        edge_phase3<0>(hiB, loB, b_e, EcolH, EcolL, mask_s, wave, lane, mrow, quad, Esum_s);
    else if (ntmax == 1)
        edge_phase3<1>(hiB, loB, b_e, EcolH, EcolL, mask_s, wave, lane, mrow, quad, Esum_s);
    else if (ntmax == 2)
        edge_phase3<2>(hiB, loB, b_e, EcolH, EcolL, mask_s, wave, lane, mrow, quad, Esum_s);
    else
        edge_phase3<3>(hiB, loB, b_e, EcolH, EcolL, mask_s, wave, lane, mrow, quad, Esum_s);

    // gate biases (shared across the 3 nodes)
    float bihc = 0.0f, bhhc = 0.0f;
    if (tid < 3 * HH) { bihc = b_ih[tid]; bhhc = b_hh[tid]; }

    // hv_p = relu(h_p @ W_h + b_h) * maskh_p  (wave p handles node p)
    if (wave < P3) {
        const int node = node0 + wave;
        const float a = (lane < NA) ? A[(size_t)node * NA + lane] : 0.0f;
        const unsigned long long mrowm = __ballot(a != 0.0f);
        const float maskh = (mrowm != 0ull) ? 1.0f : 0.0f;
        const float hr = h[(size_t)node * HIN + lane];
        float acc = b_h[lane];
        #pragma unroll
        for (int k = 0; k < HIN; ++k)
            acc = fmaf(__shfl(hr, k), W_h[k * HH + lane], acc);
        hc_s[wave * HH + lane] = fmaxf(acc, 0.0f) * maskh;
    }
    __syncthreads();

    // ---- 5 GRUCell iterations for 3 nodes; weights streamed once per iter ----
    #pragma unroll 1
    for (int it = 0; it < NCELLS; ++it) {
        if (tid < 192) {   // M[p][g] = Esum[p][g,:] . hc[p]; 4 threads per (p,g)
            const int p = tid >> 6, s = tid & 63, g = s >> 2, q = s & 3;
            const float* ep = Esum_s + p * ESTR + g * 68 + q * 16;
            const float* hp = hc_s + p * HH + q * 16;
            const float4v e0 = *(const float4v*)(ep),     h0 = *(const float4v*)(hp);
            const float4v e1 = *(const float4v*)(ep + 4), h1 = *(const float4v*)(hp + 4);
            const float4v e2 = *(const float4v*)(ep + 8), h2 = *(const float4v*)(hp + 8);
            const float4v e3 = *(const float4v*)(ep + 12), h3 = *(const float4v*)(hp + 12);
            float pp = e0[0] * h0[0];
            pp = fmaf(e0[1], h0[1], pp); pp = fmaf(e0[2], h0[2], pp); pp = fmaf(e0[3], h0[3], pp);
            pp = fmaf(e1[0], h1[0], pp); pp = fmaf(e1[1], h1[1], pp);
            pp = fmaf(e1[2], h1[2], pp); pp = fmaf(e1[3], h1[3], pp);
            pp = fmaf(e2[0], h2[0], pp); pp = fmaf(e2[1], h2[1], pp);
            pp = fmaf(e2[2], h2[2], pp); pp = fmaf(e2[3], h2[3], pp);
            pp = fmaf(e3[0], h3[0], pp); pp = fmaf(e3[1], h3[1], pp);
            pp = fmaf(e3[2], h3[2], pp); pp = fmaf(e3[3], h3[3], pp);
            pp += __shfl_xor(pp, 1);
            pp += __shfl_xor(pp, 2);
            if (q == 0) M_s[p * HG + g] = pp;
        }
        __syncthreads();
        if (tid < 192) {   // gate column c=tid for ALL 3 nodes: weights loaded once
            const float4* gp = gw4 + tid;
            float gi0 = bihc, gi1 = bihc, gi2 = bihc;
            #pragma unroll
            for (int jj = 0; jj < 4; ++jj) {
                const float4 w = gp[jj * 192];
                const float4v m0 = *(const float4v*)(M_s + 0 * HG + 4 * jj);
                const float4v m1 = *(const float4v*)(M_s + 1 * HG + 4 * jj);
                const float4v m2 = *(const float4v*)(M_s + 2 * HG + 4 * jj);
                gi0 = fmaf(m0[0], w.x, gi0); gi0 = fmaf(m0[1], w.y, gi0);
                gi0 = fmaf(m0[2], w.z, gi0); gi0 = fmaf(m0[3], w.w, gi0);
                gi1 = fmaf(m1[0], w.x, gi1); gi1 = fmaf(m1[1], w.y, gi1);
                gi1 = fmaf(m1[2], w.z, gi1); gi1 = fmaf(m1[3], w.w, gi1);
                gi2 = fmaf(m2[0], w.x, gi2); gi2 = fmaf(m2[1], w.y, gi2);
                gi2 = fmaf(m2[2], w.z, gi2); gi2 = fmaf(m2[3], w.w, gi2);
            }
            float gh0 = bhhc, gh1 = bhhc, gh2 = bhhc;
            #pragma unroll
            for (int jj = 4; jj < 20; ++jj) {
                const float4 w = gp[jj * 192];
                const float4v h0 = *(const float4v*)(hc_s + 0 * HH + 4 * (jj - 4));
                const float4v h1 = *(const float4v*)(hc_s + 1 * HH + 4 * (jj - 4));
                const float4v h2 = *(const float4v*)(hc_s + 2 * HH + 4 * (jj - 4));
                gh0 = fmaf(h0[0], w.x, gh0); gh0 = fmaf(h0[1], w.y, gh0);
                gh0 = fmaf(h0[2], w.z, gh0); gh0 = fmaf(h0[3], w.w, gh0);
                gh1 = fmaf(h1[0], w.x, gh1); gh1 = fmaf(h1[1], w.y, gh1);
                gh1 = fmaf(h1[2], w.z, gh1); gh1 = fmaf(h1[3], w.w, gh1);
                gh2 = fmaf(h2[0], w.x, gh2); gh2 = fmaf(h2[1], w.y, gh2);
                gh2 = fmaf(h2[2], w.z, gh2); gh2 = fmaf(h2[3], w.w, gh2);
            }
            if (tid < 2 * HH) {          // r,z need only the sum
                gsum_s[0 * 2 * HH + tid] = gi0 + gh0;
                gsum_s[1 * 2 * HH + tid] = gi1 + gh1;
                gsum_s[2 * 2 * HH + tid] = gi2 + gh2;
            } else {
                const int c = tid - 2 * HH;
                gin_s[0 * HH + c] = gi0; ghn_s[0 * HH + c] = gh0;
                gin_s[1 * HH + c] = gi1; ghn_s[1 * HH + c] = gh1;
                gin_s[2 * HH + c] = gi2; ghn_s[2 * HH + c] = gh2;
            }
        }
        __syncthreads();
        if (tid < 192) {   // update: thread (p,c)
            const int p = tid >> 6, c = tid & 63;
            const float r = 1.0f / (1.0f + __expf(-gsum_s[p * 2 * HH + c]));
            const float z = 1.0f / (1.0f + __expf(-gsum_s[p * 2 * HH + HH + c]));
            const float nin = gin_s[p * HH + c] + r * ghn_s[p * HH + c];
            const float n = 1.0f - 2.0f / (__expf(2.0f * nin) + 1.0f);  // tanh
            hc_s[p * HH + c] = (1.0f - z) * n + z * hc_s[p * HH + c];
        }
        __syncthreads();
    }

    if (tid < 192) out[(size_t)node0 * HH + tid] = hc_s[tid];
}

extern "C" void kernel_launch(void* const* d_in, const int* in_sizes, int n_in,
                              void* d_out, int out_size, void* d_ws, size_t ws_size,
                              hipStream_t stream) {
    const float* A    = (const float*)d_in[0];
    const float* h    = (const float*)d_in[1];
    const float* E    = (const float*)d_in[2];
    const float* W_h  = (const float*)d_in[3];
    const float* b_h  = (const float*)d_in[4];
    const float* W_e  = (const float*)d_in[5];
    const float* b_e  = (const float*)d_in[6];
    const float* W_ih = (const float*)d_in[7];
    const float* b_ih = (const float*)d_in[8];
    const float* W_hh = (const float*)d_in[9];
    const float* b_hh = (const float*)d_in[10];
    unsigned short* hiB = (unsigned short*)d_ws;            // 64 KB
    unsigned short* loB = hiB + 32768;                      // 64 KB
    float4* gw4 = (float4*)(loB + 32768);                   // 61.4 KB
    float* out = (float*)d_out;

    hipLaunchKernelGGL(prep, dim3(144), dim3(256), 0, stream,
                       W_e, W_ih, W_hh, hiB, loB, gw4);
    hipLaunchKernelGGL(fused_kernel, dim3(NB * NA / P3), dim3(256), 0, stream,
                       A, h, E, W_h, b_h, b_e, b_ih, b_hh, hiB, loB, gw4, out);
}